// Round 2
// baseline (57.713 us; speedup 1.0000x reference)
//
#include <hip/hip_runtime.h>
#include <math.h>

// Problem constants (fixed by the reference)
constexpr int D_MODEL = 1024;
constexpr int D_STATE = 64;
constexpr int SEQ_L   = 2048;
constexpr int BLOCK   = 256;                 // threads per block (one l each)
constexpr int LBLKS   = SEQ_L / BLOCK;       // 8 l-chunks per d row

template <bool WRITE_COMPLEX>
__global__ __launch_bounds__(BLOCK) void s4_cauchy_kernel(
    const float* __restrict__ log_dt,   // (D)
    const float* __restrict__ A_real,   // (D,N)
    const float* __restrict__ A_imag,   // (D,N)
    const float* __restrict__ C,        // (D,N,2)
    float* __restrict__ out)            // (D,L) real part, or interleaved if WRITE_COMPLEX
{
    __shared__ float s_abr[D_STATE];
    __shared__ float s_abi[D_STATE];
    __shared__ float s_nr [D_STATE];
    __shared__ float s_ni [D_STATE];

    const int d    = blockIdx.x / LBLKS;
    const int lblk = blockIdx.x % LBLKS;
    const int tid  = threadIdx.x;

    // ---- per-(d,n) precompute: A_bar, num = C * B_bar  (64 lanes do it) ----
    if (tid < D_STATE) {
        const int n = tid;
        const float dt = __expf(log_dt[d]);
        const float ar = A_real[d * D_STATE + n];
        const float ai = A_imag[d * D_STATE + n];
        // x = dt*A/2
        const float xr = 0.5f * dt * ar;
        const float xi = 0.5f * dt * ai;
        // den = 1 - x
        const float dr = 1.0f - xr;
        const float di = -xi;
        const float inv = 1.0f / (dr * dr + di * di);   // once per (d,n): full precision
        // A_bar = (1+x)/(1-x) = (1+x)*conj(den)*inv
        const float pr = 1.0f + xr;
        const float pi = xi;
        const float abr = (pr * dr + pi * di) * inv;
        const float abi = (pi * dr - pr * di) * inv;
        // B_bar = dt/(1-x) = dt*conj(den)*inv
        const float bbr =  dt * dr * inv;
        const float bbi = -dt * di * inv;
        // num = Cc * B_bar,  Cc = C[...,0] + i C[...,1]
        const float cr = C[(d * D_STATE + n) * 2 + 0];
        const float ci = C[(d * D_STATE + n) * 2 + 1];
        s_abr[n] = abr;
        s_abi[n] = abi;
        s_nr[n]  = cr * bbr - ci * bbi;
        s_ni[n]  = cr * bbi + ci * bbr;
    }
    __syncthreads();

    // ---- each thread: one l, sum over n ----
    const int l = lblk * BLOCK + tid;
    const float theta = (2.0f * 3.14159265358979323846f * (float)l) / (float)SEQ_L;
    float sz, cz;
    __sincosf(theta, &sz, &cz);
    const float zr = cz;    // z_inv = exp(-i*theta)
    const float zi = -sz;

    float accr = 0.0f, acci = 0.0f;

#pragma unroll
    for (int n = 0; n < D_STATE; ++n) {
        const float abr = s_abr[n];   // broadcast reads: all lanes same addr
        const float abi = s_abi[n];
        const float nr  = s_nr[n];
        const float ni  = s_ni[n];
        // denom = 1 - A_bar * z_inv
        const float dr = 1.0f - (abr * zr - abi * zi);
        const float di = -(abr * zi + abi * zr);
        const float inv = __builtin_amdgcn_rcpf(dr * dr + di * di);  // v_rcp_f32
        // acc += num * conj(denom) * inv
        accr += (nr * dr + ni * di) * inv;
        acci += (ni * dr - nr * di) * inv;
    }

    if (WRITE_COMPLEX) {
        float2* o = reinterpret_cast<float2*>(out);
        o[d * SEQ_L + l] = make_float2(accr, acci);
    } else {
        // harness keeps only the real part (out_size == D*L floats)
        out[d * SEQ_L + l] = accr;
    }
}

extern "C" void kernel_launch(void* const* d_in, const int* in_sizes, int n_in,
                              void* d_out, int out_size, void* d_ws, size_t ws_size,
                              hipStream_t stream) {
    const float* log_dt = (const float*)d_in[0];
    const float* A_real = (const float*)d_in[1];
    const float* A_imag = (const float*)d_in[2];
    const float* C      = (const float*)d_in[3];
    float* out = (float*)d_out;

    dim3 grid(D_MODEL * LBLKS);
    dim3 block(BLOCK);
    if (out_size >= 2 * D_MODEL * SEQ_L) {
        // full complex64 layout (interleaved re,im)
        s4_cauchy_kernel<true><<<grid, block, 0, stream>>>(log_dt, A_real, A_imag, C, out);
    } else {
        // real part only (out_size == D_MODEL*SEQ_L floats)
        s4_cauchy_kernel<false><<<grid, block, 0, stream>>>(log_dt, A_real, A_imag, C, out);
    }
}

// Round 4
// 33.777 us; speedup vs baseline: 1.7086x; 1.7086x over previous
//
#include <hip/hip_runtime.h>
#include <math.h>

// Problem constants (fixed by the reference)
constexpr int D_MODEL = 1024;
constexpr int D_STATE = 64;
constexpr int SEQ_L   = 2048;
constexpr int BLOCK   = 256;
constexpr int IPT     = 8;    // l-values per thread; BLOCK*IPT == SEQ_L -> 1 block per d

// ---------------- fast path: real part only (harness keeps Re(H_z)) ----------
// NOTE: denominator MUST be computed as dr^2+di^2 with dr = 1 - Re(A*z) formed
// BEFORE squaring. The |z|=1 shortcut mag = (1+|A|^2) - 2*Re(A*z) cancels
// catastrophically at resonance (true mag ~ (1-|A|)^2 ~ 2.5e-7 vs ~2-sized
// terms) and produced absmax 7.5 in round 3.
__global__ __launch_bounds__(BLOCK) void s4_cauchy_real_kernel(
    const float* __restrict__ log_dt,   // (D)
    const float* __restrict__ A_real,   // (D,N)
    const float* __restrict__ A_imag,   // (D,N)
    const float* __restrict__ C,        // (D,N,2)
    float* __restrict__ out)            // (D,L) float32 = Re(H_z)
{
    __shared__ float s_abr[D_STATE];
    __shared__ float s_abi[D_STATE];
    __shared__ float s_nr [D_STATE];
    __shared__ float s_ni [D_STATE];

    const int d   = blockIdx.x;
    const int tid = threadIdx.x;

    if (tid < D_STATE) {
        const int n = tid;
        const float dt = __expf(log_dt[d]);
        const float ar = A_real[d * D_STATE + n];
        const float ai = A_imag[d * D_STATE + n];
        const float xr = 0.5f * dt * ar;          // x = dt*A/2
        const float xi = 0.5f * dt * ai;
        const float dr = 1.0f - xr;               // den = 1 - x
        const float di = -xi;
        const float inv = 1.0f / (dr * dr + di * di);
        const float pr = 1.0f + xr;               // A_bar = (1+x)/(1-x)
        const float pi = xi;
        const float abr = (pr * dr + pi * di) * inv;
        const float abi = (pi * dr - pr * di) * inv;
        const float bbr =  dt * dr * inv;         // B_bar = dt/(1-x)
        const float bbi = -dt * di * inv;
        const float cr = C[(d * D_STATE + n) * 2 + 0];
        const float ci = C[(d * D_STATE + n) * 2 + 1];
        s_abr[n] = abr;
        s_abi[n] = abi;
        s_nr[n]  = cr * bbr - ci * bbi;           // num = Cc * B_bar
        s_ni[n]  = cr * bbi + ci * bbr;
    }
    __syncthreads();

    // each thread owns IPT l-values: l = tid + k*BLOCK (coalesced stores)
    float zr[IPT], zi[IPT], acc[IPT];
#pragma unroll
    for (int k = 0; k < IPT; ++k) {
        const int l = tid + k * BLOCK;
        const float theta = (2.0f * 3.14159265358979323846f * (float)l) / (float)SEQ_L;
        float s, c;
        __sincosf(theta, &s, &c);
        zr[k] = c;                                // z_inv = exp(-i*theta)
        zi[k] = -s;
        acc[k] = 0.0f;
    }

    // Re(H) = sum_n (nr*dr + ni*di) / (dr^2 + di^2),
    //   dr = 1 - Re(A_bar*z_inv), di = -Im(A_bar*z_inv)
#pragma unroll 4
    for (int n = 0; n < D_STATE; ++n) {
        const float abr = s_abr[n];               // wave-uniform broadcast reads
        const float abi = s_abi[n];
        const float nr  = s_nr[n];
        const float ni  = s_ni[n];
#pragma unroll
        for (int k = 0; k < IPT; ++k) {
            const float dr  = fmaf(-abr, zr[k], fmaf(abi, zi[k], 1.0f));
            const float di  = fmaf(-abr, zi[k], (-abi) * zr[k]);
            const float mag = fmaf(di, di, dr * dr);
            const float num = fmaf(ni, di, nr * dr);
            acc[k] = fmaf(num, __builtin_amdgcn_rcpf(mag), acc[k]);
        }
    }

#pragma unroll
    for (int k = 0; k < IPT; ++k)
        out[d * SEQ_L + tid + k * BLOCK] = acc[k];
}

// ---------------- fallback: full complex output (if harness ever wants it) ---
__global__ __launch_bounds__(BLOCK) void s4_cauchy_complex_kernel(
    const float* __restrict__ log_dt, const float* __restrict__ A_real,
    const float* __restrict__ A_imag, const float* __restrict__ C,
    float* __restrict__ out)
{
    __shared__ float s_abr[D_STATE], s_abi[D_STATE], s_nr[D_STATE], s_ni[D_STATE];
    const int d    = blockIdx.x / (SEQ_L / BLOCK);
    const int lblk = blockIdx.x % (SEQ_L / BLOCK);
    const int tid  = threadIdx.x;
    if (tid < D_STATE) {
        const int n = tid;
        const float dt = __expf(log_dt[d]);
        const float ar = A_real[d * D_STATE + n], ai = A_imag[d * D_STATE + n];
        const float xr = 0.5f * dt * ar, xi = 0.5f * dt * ai;
        const float dr = 1.0f - xr, di = -xi;
        const float inv = 1.0f / (dr * dr + di * di);
        const float pr = 1.0f + xr, pi = xi;
        s_abr[n] = (pr * dr + pi * di) * inv;
        s_abi[n] = (pi * dr - pr * di) * inv;
        const float bbr = dt * dr * inv, bbi = -dt * di * inv;
        const float cr = C[(d * D_STATE + n) * 2 + 0], ci = C[(d * D_STATE + n) * 2 + 1];
        s_nr[n] = cr * bbr - ci * bbi;
        s_ni[n] = cr * bbi + ci * bbr;
    }
    __syncthreads();
    const int l = lblk * BLOCK + tid;
    const float theta = (2.0f * 3.14159265358979323846f * (float)l) / (float)SEQ_L;
    float s, c; __sincosf(theta, &s, &c);
    const float zr = c, zi = -s;
    float accr = 0.f, acci = 0.f;
#pragma unroll
    for (int n = 0; n < D_STATE; ++n) {
        const float abr = s_abr[n], abi = s_abi[n], nr = s_nr[n], ni = s_ni[n];
        const float dr = 1.0f - (abr * zr - abi * zi);
        const float di = -(abr * zi + abi * zr);
        const float inv = __builtin_amdgcn_rcpf(dr * dr + di * di);
        accr += (nr * dr + ni * di) * inv;
        acci += (ni * dr - nr * di) * inv;
    }
    float2* o = reinterpret_cast<float2*>(out);
    o[d * SEQ_L + l] = make_float2(accr, acci);
}

extern "C" void kernel_launch(void* const* d_in, const int* in_sizes, int n_in,
                              void* d_out, int out_size, void* d_ws, size_t ws_size,
                              hipStream_t stream) {
    const float* log_dt = (const float*)d_in[0];
    const float* A_real = (const float*)d_in[1];
    const float* A_imag = (const float*)d_in[2];
    const float* C      = (const float*)d_in[3];
    float* out = (float*)d_out;

    if (out_size >= 2 * D_MODEL * SEQ_L) {
        dim3 grid(D_MODEL * (SEQ_L / BLOCK));
        s4_cauchy_complex_kernel<<<grid, dim3(BLOCK), 0, stream>>>(log_dt, A_real, A_imag, C, out);
    } else {
        dim3 grid(D_MODEL);   // one block per d; each thread does IPT l's
        s4_cauchy_real_kernel<<<grid, dim3(BLOCK), 0, stream>>>(log_dt, A_real, A_imag, C, out);
    }
}

// Round 5
// 29.508 us; speedup vs baseline: 1.9558x; 1.1447x over previous
//
#include <hip/hip_runtime.h>
#include <math.h>

// Problem constants (fixed by the reference)
constexpr int D_MODEL = 1024;
constexpr int D_STATE = 64;
constexpr int SEQ_L   = 2048;
constexpr int BLOCK   = 256;

typedef float f32x2 __attribute__((ext_vector_type(2)));

static __device__ __forceinline__ f32x2 fma2(f32x2 a, f32x2 b, f32x2 c) {
    return __builtin_elementwise_fma(a, b, c);
}

// ---------------- fast path: real part only (harness keeps Re(H_z)) ----------
// Numerics note: dr = 1 -/+ Re(A*z) is formed BEFORE squaring (the |z|=1
// shortcut mag = (1+|A|^2)-2u cancels catastrophically at resonance; round 3).
// +/-z pairing: z(l + L/2) = -z(l), so (l, l+1024) share u = A*z and ui^2.
// Batched rcp: 1/m1,1/m2 from one rcp(m1*m2); m1*m2 >= ~1e-7 since
// dr1^2+dr2^2 = 2+2*ur^2 >= 2 (both can't be at resonance).
__global__ __launch_bounds__(BLOCK) void s4_cauchy_real_kernel(
    const float* __restrict__ log_dt,   // (D)
    const float* __restrict__ A_real,   // (D,N)
    const float* __restrict__ A_imag,   // (D,N)
    const float* __restrict__ C,        // (D,N,2)
    float* __restrict__ out)            // (D,L) float32 = Re(H_z)
{
    // per-n constants pre-duplicated so packed math needs no splat movs
    __shared__ f32x2 s_ab_r[D_STATE];
    __shared__ f32x2 s_ab_i[D_STATE];
    __shared__ f32x2 s_n_r [D_STATE];
    __shared__ f32x2 s_n_i [D_STATE];

    const int d   = blockIdx.x;
    const int tid = threadIdx.x;

    if (tid < D_STATE) {
        const int n = tid;
        const float dt = __expf(log_dt[d]);
        const float ar = A_real[d * D_STATE + n];
        const float ai = A_imag[d * D_STATE + n];
        const float xr = 0.5f * dt * ar;          // x = dt*A/2
        const float xi = 0.5f * dt * ai;
        const float dr = 1.0f - xr;               // den = 1 - x
        const float di = -xi;
        const float inv = 1.0f / (dr * dr + di * di);
        const float pr = 1.0f + xr;               // A_bar = (1+x)/(1-x)
        const float pi = xi;
        const float abr = (pr * dr + pi * di) * inv;
        const float abi = (pi * dr - pr * di) * inv;
        const float bbr =  dt * dr * inv;         // B_bar = dt/(1-x)
        const float bbi = -dt * di * inv;
        const float cr = C[(d * D_STATE + n) * 2 + 0];
        const float ci = C[(d * D_STATE + n) * 2 + 1];
        const float nr = cr * bbr - ci * bbi;     // num = Cc * B_bar
        const float ni = cr * bbi + ci * bbr;
        s_ab_r[n] = (f32x2){abr, abr};
        s_ab_i[n] = (f32x2){abi, abi};
        s_n_r [n] = (f32x2){nr, nr};
        s_n_i [n] = (f32x2){ni, ni};
    }
    __syncthreads();

    // Thread owns 8 l's: l = tid + m*BLOCK, m=0..7.
    // Packed pairs over m: kp=0 -> m{0,1}, kp=1 -> m{2,3}; their -z partners
    // are m{4,5}, m{6,7} (l + 1024 = l + L/2).
    f32x2 zr2[2], zi2[2], acc2[4];
#pragma unroll
    for (int kp = 0; kp < 2; ++kp) {
#pragma unroll
        for (int j = 0; j < 2; ++j) {
            const int l = tid + (2 * kp + j) * BLOCK;
            const float theta = (2.0f * 3.14159265358979323846f * (float)l) / (float)SEQ_L;
            float s, c;
            __sincosf(theta, &s, &c);
            zr2[kp][j] = c;                        // z_inv = exp(-i*theta)
            zi2[kp][j] = -s;
        }
        acc2[kp]     = (f32x2){0.0f, 0.0f};
        acc2[kp + 2] = (f32x2){0.0f, 0.0f};
    }

#pragma unroll 2
    for (int n = 0; n < D_STATE; ++n) {
        const f32x2 ab_r = s_ab_r[n];              // wave-uniform b64 broadcast
        const f32x2 ab_i = s_ab_i[n];
        const f32x2 n_r  = s_n_r[n];
        const f32x2 n_i  = s_n_i[n];
#pragma unroll
        for (int kp = 0; kp < 2; ++kp) {
            // u = A_bar * z_inv
            const f32x2 ur = fma2(-ab_i, zi2[kp], ab_r * zr2[kp]);
            const f32x2 ui = fma2( ab_i, zr2[kp], ab_r * zi2[kp]);
            const f32x2 uisq = ui * ui;
            // +z branch: dr1 = 1 - ur, di1 = -ui
            const f32x2 dr1 = (f32x2){1.0f, 1.0f} - ur;
            // -z branch: dr2 = 1 + ur, di2 = +ui
            const f32x2 dr2 = (f32x2){1.0f, 1.0f} + ur;
            const f32x2 mag1 = fma2(dr1, dr1, uisq);
            const f32x2 mag2 = fma2(dr2, dr2, uisq);
            const f32x2 num1 = fma2(-n_i, ui, n_r * dr1);
            const f32x2 num2 = fma2( n_i, ui, n_r * dr2);
            // batched reciprocal: r = 1/(mag1*mag2)
            const f32x2 mm = mag1 * mag2;
            f32x2 r;
            r[0] = __builtin_amdgcn_rcpf(mm[0]);
            r[1] = __builtin_amdgcn_rcpf(mm[1]);
            acc2[kp]     = fma2(num1 * mag2, r, acc2[kp]);
            acc2[kp + 2] = fma2(num2 * mag1, r, acc2[kp + 2]);
        }
    }

#pragma unroll
    for (int kp = 0; kp < 2; ++kp) {
#pragma unroll
        for (int j = 0; j < 2; ++j) {
            out[d * SEQ_L + tid + (2 * kp + j) * BLOCK]        = acc2[kp][j];
            out[d * SEQ_L + tid + (2 * kp + j + 4) * BLOCK]    = acc2[kp + 2][j];
        }
    }
}

// ---------------- fallback: full complex output (if harness ever wants it) ---
__global__ __launch_bounds__(BLOCK) void s4_cauchy_complex_kernel(
    const float* __restrict__ log_dt, const float* __restrict__ A_real,
    const float* __restrict__ A_imag, const float* __restrict__ C,
    float* __restrict__ out)
{
    __shared__ float s_abr[D_STATE], s_abi[D_STATE], s_nr[D_STATE], s_ni[D_STATE];
    const int d    = blockIdx.x / (SEQ_L / BLOCK);
    const int lblk = blockIdx.x % (SEQ_L / BLOCK);
    const int tid  = threadIdx.x;
    if (tid < D_STATE) {
        const int n = tid;
        const float dt = __expf(log_dt[d]);
        const float ar = A_real[d * D_STATE + n], ai = A_imag[d * D_STATE + n];
        const float xr = 0.5f * dt * ar, xi = 0.5f * dt * ai;
        const float dr = 1.0f - xr, di = -xi;
        const float inv = 1.0f / (dr * dr + di * di);
        const float pr = 1.0f + xr, pi = xi;
        s_abr[n] = (pr * dr + pi * di) * inv;
        s_abi[n] = (pi * dr - pr * di) * inv;
        const float bbr = dt * dr * inv, bbi = -dt * di * inv;
        const float cr = C[(d * D_STATE + n) * 2 + 0], ci = C[(d * D_STATE + n) * 2 + 1];
        s_nr[n] = cr * bbr - ci * bbi;
        s_ni[n] = cr * bbi + ci * bbr;
    }
    __syncthreads();
    const int l = lblk * BLOCK + tid;
    const float theta = (2.0f * 3.14159265358979323846f * (float)l) / (float)SEQ_L;
    float s, c; __sincosf(theta, &s, &c);
    const float zr = c, zi = -s;
    float accr = 0.f, acci = 0.f;
#pragma unroll
    for (int n = 0; n < D_STATE; ++n) {
        const float abr = s_abr[n], abi = s_abi[n], nr = s_nr[n], ni = s_ni[n];
        const float dr = 1.0f - (abr * zr - abi * zi);
        const float di = -(abr * zi + abi * zr);
        const float inv = __builtin_amdgcn_rcpf(dr * dr + di * di);
        accr += (nr * dr + ni * di) * inv;
        acci += (ni * dr - nr * di) * inv;
    }
    float2* o = reinterpret_cast<float2*>(out);
    o[d * SEQ_L + l] = make_float2(accr, acci);
}

extern "C" void kernel_launch(void* const* d_in, const int* in_sizes, int n_in,
                              void* d_out, int out_size, void* d_ws, size_t ws_size,
                              hipStream_t stream) {
    const float* log_dt = (const float*)d_in[0];
    const float* A_real = (const float*)d_in[1];
    const float* A_imag = (const float*)d_in[2];
    const float* C      = (const float*)d_in[3];
    float* out = (float*)d_out;

    if (out_size >= 2 * D_MODEL * SEQ_L) {
        dim3 grid(D_MODEL * (SEQ_L / BLOCK));
        s4_cauchy_complex_kernel<<<grid, dim3(BLOCK), 0, stream>>>(log_dt, A_real, A_imag, C, out);
    } else {
        dim3 grid(D_MODEL);   // one block per d; each thread does 8 l's
        s4_cauchy_real_kernel<<<grid, dim3(BLOCK), 0, stream>>>(log_dt, A_real, A_imag, C, out);
    }
}